// Round 16
// baseline (379.244 us; speedup 1.0000x reference)
//
#include <hip/hip_runtime.h>
#include <hip/hip_bf16.h>
#include <cstdint>

typedef unsigned short U16;
typedef float f32x4 __attribute__((ext_vector_type(4)));
typedef __bf16 bf16x8 __attribute__((ext_vector_type(8)));

#define DEVINL __device__ __forceinline__

DEVINL U16 f2bf(float f) {
    unsigned u = __float_as_uint(f);
    return (U16)((u + 0x7FFFu + ((u >> 16) & 1u)) >> 16);  // RN-even
}
DEVINL float bf2f(U16 s) { return __uint_as_float(((unsigned)s) << 16); }

DEVINL void gld16(const void* g, void* l) {
    __builtin_amdgcn_global_load_lds(
        (const __attribute__((address_space(1))) void*)g,
        (__attribute__((address_space(3))) void*)l, 16, 0, 0);
}

#define MFMA_BF16 __builtin_amdgcn_mfma_f32_16x16x32_bf16

// ---------------- weight transpose + cast: wt[n][k] = (bf16) w[k][n] ----------------
__global__ __launch_bounds__(256) void tcast_kernel(const float* __restrict__ w,
                                                    U16* __restrict__ wt, int K, int N) {
    __shared__ float tile[32][33];
    int n0 = blockIdx.x * 32, k0 = blockIdx.y * 32;
    int tx = threadIdx.x, ty = threadIdx.y;  // 32 x 8
#pragma unroll
    for (int i = 0; i < 32; i += 8) tile[ty + i][tx] = w[(size_t)(k0 + ty + i) * N + (n0 + tx)];
    __syncthreads();
#pragma unroll
    for (int i = 0; i < 32; i += 8) wt[(size_t)(n0 + ty + i) * K + (k0 + tx)] = f2bf(tile[tx][ty + i]);
}

// ---------------- LayerNorm over 512, one wave per row, bf16 out (LN1 only) ----------------
__global__ __launch_bounds__(256) void ln_kernel(const float* __restrict__ x,
                                                 const float* __restrict__ g,
                                                 const float* __restrict__ b,
                                                 U16* __restrict__ out) {
    int lane = threadIdx.x & 63;
    size_t row = (size_t)blockIdx.x * 4 + (threadIdx.x >> 6);
    const float4* xr = (const float4*)(x + row * 512);
    float4 v0 = xr[lane], v1 = xr[lane + 64];
    float s = (v0.x + v0.y) + (v0.z + v0.w) + (v1.x + v1.y) + (v1.z + v1.w);
    float sq = (v0.x * v0.x + v0.y * v0.y + v0.z * v0.z + v0.w * v0.w) +
               (v1.x * v1.x + v1.y * v1.y + v1.z * v1.z + v1.w * v1.w);
#pragma unroll
    for (int m = 1; m < 64; m <<= 1) { s += __shfl_xor(s, m); sq += __shfl_xor(sq, m); }
    float mu = s * (1.f / 512.f);
    float var = sq * (1.f / 512.f) - mu * mu;
    float rs = rsqrtf(var + 1e-5f);
    const float4* g4 = (const float4*)g;
    const float4* b4 = (const float4*)b;
    float4 gv = g4[lane], bv = b4[lane];
    ushort4 o;
    o.x = f2bf((v0.x - mu) * rs * gv.x + bv.x);
    o.y = f2bf((v0.y - mu) * rs * gv.y + bv.y);
    o.z = f2bf((v0.z - mu) * rs * gv.z + bv.z);
    o.w = f2bf((v0.w - mu) * rs * gv.w + bv.w);
    ((ushort4*)(out + row * 512))[lane] = o;
    gv = g4[lane + 64]; bv = b4[lane + 64];
    o.x = f2bf((v1.x - mu) * rs * gv.x + bv.x);
    o.y = f2bf((v1.y - mu) * rs * gv.y + bv.y);
    o.z = f2bf((v1.z - mu) * rs * gv.z + bv.z);
    o.w = f2bf((v1.w - mu) * rs * gv.w + bv.w);
    ((ushort4*)(out + row * 512))[lane + 64] = o;
}

// ================= R9-exact 128x128 ring-2 GEMM (best measured for FC1/FC2) =================
// 256 threads = 4 waves (2x2), wave tile 64x64, BK=32, ring-2 x 16KB LDS, 3-4 blocks/CU.
// EPI 1: fp32 out (bias+resid); EPI 2: bf16 out (bias+gelu-tanh)
template <int EPI, int K>
__global__ __launch_bounds__(256, 4) void gemm128(const U16* __restrict__ A,
                                                  const U16* __restrict__ Bt,
                                                  const float* __restrict__ bias,
                                                  const float* __restrict__ resid,
                                                  U16* __restrict__ outb,
                                                  float* __restrict__ outf,
                                                  int M, int N, int gridN) {
    __shared__ __align__(16) U16 smem[16384];

    const int tid = threadIdx.x;
    const int lane = tid & 63, wv = tid >> 6;
    const int lo = lane & 15, hi = lane >> 4;
    const int wm = wv >> 1, wn = wv & 1;

    const int nwg = gridDim.x, bid = blockIdx.x;
    const int swzb = (bid & 7) * (nwg >> 3) + (bid >> 3);
    const int bn = swzb % gridN, bm = swzb / gridN;

    const int sr = tid >> 2;
    const int lc = (tid & 3) ^ ((sr >> 1) & 3);
    const U16* gA0 = A + (size_t)(bm * 128 + sr) * K + lc * 8;
    const U16* gA1 = gA0 + (size_t)64 * K;
    const U16* gB0 = Bt + (size_t)(bn * 128 + sr) * K + lc * 8;
    const U16* gB1 = gB0 + (size_t)64 * K;

#define STAGE(t2)                                                     \
    do {                                                              \
        U16* _l = smem + ((t2) & 1) * 8192 + tid * 8;                 \
        gld16(gA0 + (t2) * 32, _l);                                   \
        gld16(gA1 + (t2) * 32, _l + 2048);                            \
        gld16(gB0 + (t2) * 32, _l + 4096);                            \
        gld16(gB1 + (t2) * 32, _l + 6144);                            \
    } while (0)

    const int ck = (hi ^ ((lo >> 1) & 3)) << 3;

    f32x4 acc[4][4] = {};

    constexpr int NT = K >> 5;
    static_assert(NT >= 16 && (NT % 16) == 0, "K must be a multiple of 512");

    STAGE(0);

    auto tile = [&](int t, bool pf) __attribute__((always_inline)) {
        if (pf) {
            STAGE(t + 1);
            asm volatile("s_waitcnt vmcnt(4)" ::: "memory");
        } else {
            asm volatile("s_waitcnt vmcnt(0)" ::: "memory");
        }
        __builtin_amdgcn_s_barrier();

        const int cb = (t & 1) * 8192;
        const U16* Ab = smem + cb + (wm * 64 + lo) * 32 + ck;
        const U16* Bb = smem + cb + 4096 + (wn * 64 + lo) * 32 + ck;

        bf16x8 af[4], bg[4];
#pragma unroll
        for (int i = 0; i < 4; ++i) af[i] = *(const bf16x8*)(Ab + i * 512);
#pragma unroll
        for (int j = 0; j < 4; ++j) bg[j] = *(const bf16x8*)(Bb + j * 512);

        __builtin_amdgcn_s_setprio(1);
#pragma unroll
        for (int i = 0; i < 4; ++i)
#pragma unroll
            for (int j = 0; j < 4; ++j)
                acc[i][j] = MFMA_BF16(af[i], bg[j], acc[i][j], 0, 0, 0);
        __builtin_amdgcn_s_setprio(0);
        __builtin_amdgcn_s_barrier();
    };

    for (int t0 = 0; t0 + 16 < NT; t0 += 16) {
#pragma unroll
        for (int tt = 0; tt < 16; ++tt) tile(t0 + tt, true);
    }
#pragma unroll
    for (int tt = 0; tt < 16; ++tt) {
        const int t = NT - 16 + tt;
        tile(t, t + 1 < NT);
    }

    const int row0 = bm * 128 + wm * 64 + hi * 4;
    const int col0 = bn * 128 + wn * 64 + lo;
    float bc[4];
#pragma unroll
    for (int j = 0; j < 4; ++j) bc[j] = bias[col0 + j * 16];

    if (EPI == 1) {
#pragma unroll
        for (int i = 0; i < 4; ++i)
#pragma unroll
            for (int r = 0; r < 4; ++r) {
                const size_t rowb = (size_t)(row0 + i * 16 + r) * N;
#pragma unroll
                for (int j = 0; j < 4; ++j) {
                    const size_t idx = rowb + col0 + j * 16;
                    outf[idx] = acc[i][j][r] + bc[j] + resid[idx];
                }
            }
    } else {
#pragma unroll
        for (int i = 0; i < 4; ++i)
#pragma unroll
            for (int j = 0; j < 4; ++j)
#pragma unroll
                for (int r = 0; r < 4; ++r) {
                    float v = acc[i][j][r] + bc[j];
                    if (EPI == 2) {
                        float u = v * (0.7978845608028654f + 0.0356774081f * v * v);
                        v = v / (1.f + __expf(-2.f * u));
                    }
                    outb[(size_t)(row0 + i * 16 + r) * N + col0 + j * 16] = f2bf(v);
                }
    }
#undef STAGE
}

// ================= R15-exact 256x256 4-phase GEMM (best measured for QKV) =================
template <int EPI, int K>
__global__ __launch_bounds__(512, 1) void gemm256(const U16* __restrict__ A,
                                                  const U16* __restrict__ Bt,
                                                  const float* __restrict__ bias,
                                                  const float* __restrict__ resid,
                                                  U16* __restrict__ outb,
                                                  float* __restrict__ outf,
                                                  int M, int N, int gridN) {
    __shared__ __align__(16) U16 smem[65536];

    const int tid = threadIdx.x;
    const int lane = tid & 63, wv = tid >> 6;
    const int lo = lane & 15, hi = lane >> 4;
    const int wm = wv >> 2, wn = wv & 3;

    const int nwg = gridDim.x, bid = blockIdx.x;
    const int swzb = (bid & 7) * (nwg >> 3) + (bid >> 3);
    const int bn = swzb % gridN, bm = swzb / gridN;

    const int sr2 = tid >> 3;
    const int lc8 = (tid & 7) ^ (sr2 & 7);
    const U16* gAh = A + (size_t)(bm * 256 + sr2) * K + lc8 * 8;
    const U16* gBh = Bt + (size_t)(bn * 256 + sr2) * K + lc8 * 8;

#define SA0(t)                                                              \
    do { U16* _l = smem + ((t) & 1) * 32768 + tid * 8;                      \
         gld16(gAh + (t) * 64, _l);                                         \
         gld16(gAh + (size_t)64 * K + (t) * 64, _l + 4096); } while (0)
#define SA1(t)                                                              \
    do { U16* _l = smem + ((t) & 1) * 32768 + 8192 + tid * 8;               \
         gld16(gAh + (size_t)128 * K + (t) * 64, _l);                       \
         gld16(gAh + (size_t)192 * K + (t) * 64, _l + 4096); } while (0)
#define SB0(t)                                                              \
    do { U16* _l = smem + ((t) & 1) * 32768 + 16384 + tid * 8;              \
         gld16(gBh + (t) * 64, _l);                                         \
         gld16(gBh + (size_t)64 * K + (t) * 64, _l + 4096); } while (0)
#define SB1(t)                                                              \
    do { U16* _l = smem + ((t) & 1) * 32768 + 24576 + tid * 8;              \
         gld16(gBh + (size_t)128 * K + (t) * 64, _l);                       \
         gld16(gBh + (size_t)192 * K + (t) * 64, _l + 4096); } while (0)

    const int ck0 = (hi ^ (lo & 7)) << 3;
    const int ck1 = ((4 | hi) ^ (lo & 7)) << 3;
    const int abase = wm * 8192 + lo * 64;
    const int bbase = 16384 + (wn >> 1) * 8192 + ((wn & 1) * 64 + lo) * 64;

    f32x4 acc[8][4] = {};

    constexpr int NT = K >> 6;
    static_assert(NT >= 4 && (NT % 4) == 0, "K must be a multiple of 256");

    SA0(0); SA1(0); SB0(0); SB1(0);
    SB0(1); SB1(1);
    asm volatile("s_waitcnt vmcnt(4)" ::: "memory");
    __builtin_amdgcn_s_barrier();

#define ITER(s)                                                                 \
    do {                                                                        \
        const int _cb = ((s) & 1) * 32768;                                      \
        const U16* _Ab = smem + _cb + abase;                                    \
        const U16* _Bb = smem + _cb + bbase;                                    \
        bf16x8 af[4][2], bg[4][2], af2[4][2];                                   \
        _Pragma("unroll") for (int i = 0; i < 4; ++i) {                         \
            af[i][0] = *(const bf16x8*)(_Ab + i * 1024 + ck0);                  \
            af[i][1] = *(const bf16x8*)(_Ab + i * 1024 + ck1);                  \
        }                                                                       \
        _Pragma("unroll") for (int j = 0; j < 2; ++j) {                         \
            bg[j][0] = *(const bf16x8*)(_Bb + j * 1024 + ck0);                  \
            bg[j][1] = *(const bf16x8*)(_Bb + j * 1024 + ck1);                  \
        }                                                                       \
        if ((s) + 1 < NT) SA0((s) + 1);                                         \
        __builtin_amdgcn_s_barrier();                                           \
        __builtin_amdgcn_s_setprio(1);                                          \
        _Pragma("unroll") for (int i = 0; i < 4; ++i)                           \
            _Pragma("unroll") for (int j = 0; j < 2; ++j) {                     \
                acc[i][j] = MFMA_BF16(af[i][0], bg[j][0], acc[i][j], 0, 0, 0);  \
                acc[i][j] = MFMA_BF16(af[i][1], bg[j][1], acc[i][j], 0, 0, 0);  \
            }                                                                   \
        __builtin_amdgcn_s_setprio(0);                                          \
        __builtin_amdgcn_s_barrier();                                           \
        _Pragma("unroll") for (int j = 2; j < 4; ++j) {                         \
            bg[j][0] = *(const bf16x8*)(_Bb + j * 1024 + ck0);                  \
            bg[j][1] = *(const bf16x8*)(_Bb + j * 1024 + ck1);                  \
        }                                                                       \
        if ((s) + 1 < NT) SA1((s) + 1);                                         \
        __builtin_amdgcn_s_barrier();                                           \
        __builtin_amdgcn_s_setprio(1);                                          \
        _Pragma("unroll") for (int i = 0; i < 4; ++i)                           \
            _Pragma("unroll") for (int j = 2; j < 4; ++j) {                     \
                acc[i][j] = MFMA_BF16(af[i][0], bg[j][0], acc[i][j], 0, 0, 0);  \
                acc[i][j] = MFMA_BF16(af[i][1], bg[j][1], acc[i][j], 0, 0, 0);  \
            }                                                                   \
        __builtin_amdgcn_s_setprio(0);                                          \
        __builtin_amdgcn_s_barrier();                                           \
        _Pragma("unroll") for (int i = 0; i < 4; ++i) {                         \
            af2[i][0] = *(const bf16x8*)(_Ab + 4096 + i * 1024 + ck0);          \
            af2[i][1] = *(const bf16x8*)(_Ab + 4096 + i * 1024 + ck1);          \
        }                                                                       \
        if ((s) + 2 < NT) SB0((s) + 2);                                         \
        __builtin_amdgcn_s_barrier();                                           \
        __builtin_amdgcn_s_setprio(1);                                          \
        _Pragma("unroll") for (int i = 0; i < 4; ++i)                           \
            _Pragma("unroll") for (int j = 0; j < 2; ++j) {                     \
                acc[4 + i][j] = MFMA_BF16(af2[i][0], bg[j][0], acc[4 + i][j], 0, 0, 0); \
                acc[4 + i][j] = MFMA_BF16(af2[i][1], bg[j][1], acc[4 + i][j], 0, 0, 0); \
            }                                                                   \
        __builtin_amdgcn_s_setprio(0);                                          \
        __builtin_amdgcn_s_barrier();                                           \
        if ((s) + 2 < NT) SB1((s) + 2);                                         \
        __builtin_amdgcn_s_setprio(1);                                          \
        _Pragma("unroll") for (int i = 0; i < 4; ++i)                           \
            _Pragma("unroll") for (int j = 2; j < 4; ++j) {                     \
                acc[4 + i][j] = MFMA_BF16(af2[i][0], bg[j][0], acc[4 + i][j], 0, 0, 0); \
                acc[4 + i][j] = MFMA_BF16(af2[i][1], bg[j][1], acc[4 + i][j], 0, 0, 0); \
            }                                                                   \
        __builtin_amdgcn_s_setprio(0);                                          \
        if ((s) + 2 < NT) {                                                     \
            asm volatile("s_waitcnt vmcnt(4)" ::: "memory");                    \
        } else {                                                                \
            asm volatile("s_waitcnt vmcnt(0)" ::: "memory");                    \
        }                                                                       \
        __builtin_amdgcn_s_barrier();                                           \
    } while (0)

#pragma unroll
    for (int s = 0; s < NT; ++s) ITER(s);

    const int row0 = bm * 256 + wm * 128 + hi * 4;
    const int col0 = bn * 256 + wn * 64 + lo;
    float bc[4];
#pragma unroll
    for (int j = 0; j < 4; ++j) bc[j] = bias[col0 + j * 16];

    if (EPI == 1) {
#pragma unroll
        for (int i = 0; i < 8; ++i)
#pragma unroll
            for (int r = 0; r < 4; ++r) {
                const size_t rowb = (size_t)(row0 + i * 16 + r) * N;
#pragma unroll
                for (int j = 0; j < 4; ++j) {
                    const size_t idx = rowb + col0 + j * 16;
                    outf[idx] = acc[i][j][r] + bc[j] + resid[idx];
                }
            }
    } else {
#pragma unroll
        for (int i = 0; i < 8; ++i)
#pragma unroll
            for (int j = 0; j < 4; ++j)
#pragma unroll
                for (int r = 0; r < 4; ++r) {
                    float v = acc[i][j][r] + bc[j];
                    if (EPI == 2) {
                        float u = v * (0.7978845608028654f + 0.0356774081f * v * v);
                        v = v / (1.f + __expf(-2.f * u));
                    }
                    outb[(size_t)(row0 + i * 16 + r) * N + col0 + j * 16] = f2bf(v);
                }
    }
#undef ITER
#undef SA0
#undef SA1
#undef SB0
#undef SB1
}

// ================= fused proj + residual + LN2 =================
// Block = 128 rows x FULL N=512. 512 threads = 8 waves (1x8), wave tile 128x64, BK=32,
// ring-3 x 40KB LDS (120KB) + separate 9KB reduction array (no ring alias).
// K-loop = R13's proven single-barrier counted-vmcnt(5) structure (5 gld16/tile).
// Epilogue: x2 = acc + bias + x (fp32, in-register); write x2 -> d_out (FC2 resid);
// per-row LN stats via 16-lane shfl + 8-wave LDS reduce; write h2 bf16 IN-PLACE into
// hbuf (safe: full-N block => only this block touches its rows, after its K-loop).
template <int K>
__global__ __launch_bounds__(512, 1) void projln_kernel(const U16* __restrict__ A,
                                                        const U16* __restrict__ Bt,
                                                        const float* __restrict__ bias,
                                                        const float* __restrict__ x,
                                                        const float* __restrict__ g2,
                                                        const float* __restrict__ b2,
                                                        float* __restrict__ xout,
                                                        U16* __restrict__ h2out) {
    // ring buf b at b*20480 U16: A[128][32] at +0 (4096), B[512][32] at +4096 (16384)
    __shared__ __align__(16) U16 smem[61440];
    __shared__ float red[2304];  // sums[128][8], sumsq[128][8], mu[128], rs[128]

    const int tid = threadIdx.x;
    const int lane = tid & 63, wv = tid >> 6;
    const int lo = lane & 15, hi = lane >> 4;

    const int nwg = gridDim.x, bid = blockIdx.x;
    const int bm = (bid & 7) * (nwg >> 3) + (bid >> 3);  // gridN == 1

    // staging: row sr = tid>>2 (0..127), phys chunk tid&3; logical = phys ^ ((sr>>1)&3)
    const int sr = tid >> 2;
    const int lc = (tid & 3) ^ ((sr >> 1) & 3);
    const U16* gA0 = A + (size_t)(bm * 128 + sr) * K + lc * 8;
    const U16* gB0 = Bt + (size_t)sr * K + lc * 8;           // B rows 0-127
    const U16* gB1 = gB0 + (size_t)128 * K;
    const U16* gB2 = gB0 + (size_t)256 * K;
    const U16* gB3 = gB0 + (size_t)384 * K;

#define PSTAGE(t2)                                                    \
    do {                                                              \
        U16* _l = smem + ((t2) % 3) * 20480 + tid * 8;                \
        gld16(gA0 + (t2) * 32, _l);                                   \
        gld16(gB0 + (t2) * 32, _l + 4096);                            \
        gld16(gB1 + (t2) * 32, _l + 8192);                            \
        gld16(gB2 + (t2) * 32, _l + 12288);                           \
        gld16(gB3 + (t2) * 32, _l + 16384);                           \
    } while (0)

    const int ck = (hi ^ ((lo >> 1) & 3)) << 3;
    const int aoff = lo * 32 + ck;                          // + i*512
    const int boff = 4096 + (wv * 64 + lo) * 32 + ck;       // + j*512

    f32x4 acc[8][4] = {};

    constexpr int NT = K >> 5;  // 16
    static_assert(NT == 16, "projln expects K=512");

    PSTAGE(0);
    PSTAGE(1);

#define PITER(t)                                                                \
    do {                                                                        \
        if ((t) + 1 < NT) {                                                     \
            asm volatile("s_waitcnt vmcnt(5)" ::: "memory");                    \
        } else {                                                                \
            asm volatile("s_waitcnt vmcnt(0)" ::: "memory");                    \
        }                                                                       \
        __builtin_amdgcn_s_barrier();                                           \
        if ((t) + 2 < NT) PSTAGE((t) + 2);                                      \
        {                                                                       \
            const int _cb = ((t) % 3) * 20480;                                  \
            const U16* _Ab = smem + _cb + aoff;                                 \
            const U16* _Bb = smem + _cb + boff;                                 \
            bf16x8 af[8], bg[4];                                                \
            _Pragma("unroll") for (int i = 0; i < 8; ++i)                       \
                af[i] = *(const bf16x8*)(_Ab + i * 512);                        \
            _Pragma("unroll") for (int j = 0; j < 4; ++j)                       \
                bg[j] = *(const bf16x8*)(_Bb + j * 512);                        \
            __builtin_amdgcn_s_setprio(1);                                      \
            _Pragma("unroll") for (int i = 0; i < 8; ++i)                       \
                _Pragma("unroll") for (int j = 0; j < 4; ++j)                   \
                    acc[i][j] = MFMA_BF16(af[i], bg[j], acc[i][j], 0, 0, 0);    \
            __builtin_amdgcn_s_setprio(0);                                      \
        }                                                                       \
    } while (0)

#pragma unroll
    for (int t = 0; t < NT; ++t) PITER(t);

    // ---- epilogue: x2 = acc + bias + x ; d_out write ; LN stats ----
    const size_t row0g = (size_t)bm * 128;
    float bc[4];
#pragma unroll
    for (int j = 0; j < 4; ++j) bc[j] = bias[wv * 64 + j * 16 + lo];

#pragma unroll
    for (int i = 0; i < 8; ++i)
#pragma unroll
        for (int r = 0; r < 4; ++r) {
            const int row = i * 16 + hi * 4 + r;
            const size_t rowb = (row0g + row) * 512;
            float s = 0.f, sq = 0.f;
#pragma unroll
            for (int j = 0; j < 4; ++j) {
                const int col = wv * 64 + j * 16 + lo;
                float v = acc[i][j][r] + bc[j] + x[rowb + col];
                acc[i][j][r] = v;
                xout[rowb + col] = v;
                s += v; sq += v * v;
            }
#pragma unroll
            for (int m = 1; m < 16; m <<= 1) { s += __shfl_xor(s, m); sq += __shfl_xor(sq, m); }
            if (lo == 0) { red[row * 8 + wv] = s; red[1024 + row * 8 + wv] = sq; }
        }
    __syncthreads();
    if (tid < 128) {
        float s = 0.f, q = 0.f;
#pragma unroll
        for (int w = 0; w < 8; ++w) { s += red[tid * 8 + w]; q += red[1024 + tid * 8 + w]; }
        float mu = s * (1.f / 512.f);
        float var = q * (1.f / 512.f) - mu * mu;
        red[2048 + tid] = mu;
        red[2176 + tid] = rsqrtf(var + 1e-5f);
    }
    __syncthreads();
    float gv[4], bv[4];
#pragma unroll
    for (int j = 0; j < 4; ++j) {
        const int col = wv * 64 + j * 16 + lo;
        gv[j] = g2[col]; bv[j] = b2[col];
    }
#pragma unroll
    for (int i = 0; i < 8; ++i)
#pragma unroll
        for (int r = 0; r < 4; ++r) {
            const int row = i * 16 + hi * 4 + r;
            const float mu = red[2048 + row];
            const float rs = red[2176 + row];
            const size_t rowb = (row0g + row) * 512;
#pragma unroll
            for (int j = 0; j < 4; ++j) {
                const int col = wv * 64 + j * 16 + lo;
                h2out[rowb + col] = f2bf((acc[i][j][r] - mu) * rs * gv[j] + bv[j]);
            }
        }
#undef PITER
#undef PSTAGE
}

// ---------------- windowed attention: one block per (window, head) ----------------
__global__ __launch_bounds__(256) void attn_kernel(const U16* __restrict__ qkv,
                                                   U16* __restrict__ o) {
    const int blk = blockIdx.x;
    const int w = blk >> 3, h = blk & 7;
    const int tid = threadIdx.x;
    const int lane = tid & 63, wv = tid >> 6;
    const int lo = lane & 15, hi = lane >> 4;

    __shared__ __align__(16) U16 Qs[64][72];
    __shared__ __align__(16) U16 Ks[64][72];
    __shared__ __align__(16) U16 Vt[64][72];
    __shared__ __align__(16) U16 Ps[4][16][72];

    {
        const int r = tid >> 2;
        const int c0 = (tid & 3) << 4;
        const U16* p = qkv + (size_t)(w * 64 + r) * 1536 + h * 64 + c0;
        *(bf16x8*)&Ks[r][c0] = *(const bf16x8*)(p + 512);
        *(bf16x8*)&Ks[r][c0 + 8] = *(const bf16x8*)(p + 520);
        const U16* pv = p + 1024;
#pragma unroll
        for (int i = 0; i < 16; i++) Vt[c0 + i][r] = pv[i];
#pragma unroll
        for (int i = 0; i < 16; i++) Qs[r][c0 + i] = f2bf(bf2f(p[i]) * 0.125f);
    }
    __syncthreads();

    const int rb = wv * 16;
    f32x4 s[4] = {};
#pragma unroll
    for (int dc = 0; dc < 64; dc += 32) {
        bf16x8 a = *(const bf16x8*)&Qs[rb + lo][dc + hi * 8];
#pragma unroll
        for (int jb = 0; jb < 4; jb++) {
            bf16x8 bfr = *(const bf16x8*)&Ks[jb * 16 + lo][dc + hi * 8];
            s[jb] = MFMA_BF16(a, bfr, s[jb], 0, 0, 0);
        }
    }
#pragma unroll
    for (int r = 0; r < 4; r++) {
        float m = fmaxf(fmaxf(s[0][r], s[1][r]), fmaxf(s[2][r], s[3][r]));
#pragma unroll
        for (int msk = 1; msk < 16; msk <<= 1) m = fmaxf(m, __shfl_xor(m, msk));
        float e[4], sum = 0.f;
#pragma unroll
        for (int jb = 0; jb < 4; jb++) { e[jb] = __expf(s[jb][r] - m); sum += e[jb]; }
#pragma unroll
        for (int msk = 1; msk < 16; msk <<= 1) sum += __shfl_xor(sum, msk);
        float inv = 1.f / sum;
#pragma unroll
        for (int jb = 0; jb < 4; jb++) Ps[wv][hi * 4 + r][jb * 16 + lo] = f2bf(e[jb] * inv);
    }
    __syncthreads();

    f32x4 oa[4] = {};
#pragma unroll
    for (int jc = 0; jc < 64; jc += 32) {
        bf16x8 a = *(const bf16x8*)&Ps[wv][lo][jc + hi * 8];
#pragma unroll
        for (int db = 0; db < 4; db++) {
            bf16x8 bfr = *(const bf16x8*)&Vt[db * 16 + lo][jc + hi * 8];
            oa[db] = MFMA_BF16(a, bfr, oa[db], 0, 0, 0);
        }
    }
#pragma unroll
    for (int db = 0; db < 4; db++)
#pragma unroll
        for (int r = 0; r < 4; r++)
            o[(size_t)(w * 64 + rb + hi * 4 + r) * 512 + h * 64 + db * 16 + lo] = f2bf(oa[db][r]);
}

// ---------------- launch ----------------
extern "C" void kernel_launch(void* const* d_in, const int* in_sizes, int n_in,
                              void* d_out, int out_size, void* d_ws, size_t ws_size,
                              hipStream_t stream) {
    const float* x = (const float*)d_in[0];
    const float* ln1_g = (const float*)d_in[1];
    const float* ln1_b = (const float*)d_in[2];
    const float* qkv_w = (const float*)d_in[3];
    const float* qkv_b = (const float*)d_in[4];
    const float* proj_w = (const float*)d_in[5];
    const float* proj_b = (const float*)d_in[6];
    const float* ln2_g = (const float*)d_in[7];
    const float* ln2_b = (const float*)d_in[8];
    const float* fc1_w = (const float*)d_in[9];
    const float* fc1_b = (const float*)d_in[10];
    const float* fc2_w = (const float*)d_in[11];
    const float* fc2_b = (const float*)d_in[12];
    float* out = (float*)d_out;

    char* ws = (char*)d_ws;
    U16* hbuf = (U16*)ws;                               // 32768*512 bf16 (h -> o -> h2)
    U16* big = (U16*)(ws + 33554432);                   // qkv then fc1 act
    U16* wt_qkv = (U16*)(ws + 33554432 + 134217728);
    U16* wt_proj = wt_qkv + 1536 * 512;
    U16* wt_fc1 = wt_proj + 512 * 512;
    U16* wt_fc2 = wt_fc1 + 2048 * 512;

    dim3 tb(32, 8);
    tcast_kernel<<<dim3(1536 / 32, 512 / 32), tb, 0, stream>>>(qkv_w, wt_qkv, 512, 1536);
    tcast_kernel<<<dim3(512 / 32, 512 / 32), tb, 0, stream>>>(proj_w, wt_proj, 512, 512);
    tcast_kernel<<<dim3(2048 / 32, 512 / 32), tb, 0, stream>>>(fc1_w, wt_fc1, 512, 2048);
    tcast_kernel<<<dim3(512 / 32, 2048 / 32), tb, 0, stream>>>(fc2_w, wt_fc2, 2048, 512);

    ln_kernel<<<8192, 256, 0, stream>>>(x, ln1_g, ln1_b, hbuf);
    gemm256<0, 512><<<768, 512, 0, stream>>>(hbuf, wt_qkv, qkv_b, nullptr, big, nullptr, 32768, 1536, 6);
    attn_kernel<<<4096, 256, 0, stream>>>(big, hbuf);
    // fused proj + residual + LN2: writes x2 (fp32) -> d_out, h2 (bf16) in-place -> hbuf
    projln_kernel<512><<<256, 512, 0, stream>>>(hbuf, wt_proj, proj_b, x, ln2_g, ln2_b, out, hbuf);
    gemm128<2, 512><<<4096, 256, 0, stream>>>(hbuf, wt_fc1, fc1_b, nullptr, big, nullptr, 32768, 2048, 16);
    gemm128<1, 2048><<<1024, 256, 0, stream>>>(big, wt_fc2, fc2_b, out, nullptr, out, 32768, 512, 4);
}

// Round 17
// 364.592 us; speedup vs baseline: 1.0402x; 1.0402x over previous
//
#include <hip/hip_runtime.h>
#include <hip/hip_bf16.h>
#include <cstdint>

typedef unsigned short U16;
typedef float f32x4 __attribute__((ext_vector_type(4)));
typedef __bf16 bf16x8 __attribute__((ext_vector_type(8)));

#define DEVINL __device__ __forceinline__

DEVINL U16 f2bf(float f) {
    unsigned u = __float_as_uint(f);
    return (U16)((u + 0x7FFFu + ((u >> 16) & 1u)) >> 16);  // RN-even
}
DEVINL float bf2f(U16 s) { return __uint_as_float(((unsigned)s) << 16); }

DEVINL void gld16(const void* g, void* l) {
    __builtin_amdgcn_global_load_lds(
        (const __attribute__((address_space(1))) void*)g,
        (__attribute__((address_space(3))) void*)l, 16, 0, 0);
}

#define MFMA_BF16 __builtin_amdgcn_mfma_f32_16x16x32_bf16

// ---------------- weight transpose + cast: wt[n][k] = (bf16) w[k][n] ----------------
__global__ __launch_bounds__(256) void tcast_kernel(const float* __restrict__ w,
                                                    U16* __restrict__ wt, int K, int N) {
    __shared__ float tile[32][33];
    int n0 = blockIdx.x * 32, k0 = blockIdx.y * 32;
    int tx = threadIdx.x, ty = threadIdx.y;  // 32 x 8
#pragma unroll
    for (int i = 0; i < 32; i += 8) tile[ty + i][tx] = w[(size_t)(k0 + ty + i) * N + (n0 + tx)];
    __syncthreads();
#pragma unroll
    for (int i = 0; i < 32; i += 8) wt[(size_t)(n0 + ty + i) * K + (k0 + tx)] = f2bf(tile[tx][ty + i]);
}

// ---------------- LayerNorm over 512, one wave per row, bf16 out (LN1 only) ----------------
__global__ __launch_bounds__(256) void ln_kernel(const float* __restrict__ x,
                                                 const float* __restrict__ g,
                                                 const float* __restrict__ b,
                                                 U16* __restrict__ out) {
    int lane = threadIdx.x & 63;
    size_t row = (size_t)blockIdx.x * 4 + (threadIdx.x >> 6);
    const float4* xr = (const float4*)(x + row * 512);
    float4 v0 = xr[lane], v1 = xr[lane + 64];
    float s = (v0.x + v0.y) + (v0.z + v0.w) + (v1.x + v1.y) + (v1.z + v1.w);
    float sq = (v0.x * v0.x + v0.y * v0.y + v0.z * v0.z + v0.w * v0.w) +
               (v1.x * v1.x + v1.y * v1.y + v1.z * v1.z + v1.w * v1.w);
#pragma unroll
    for (int m = 1; m < 64; m <<= 1) { s += __shfl_xor(s, m); sq += __shfl_xor(sq, m); }
    float mu = s * (1.f / 512.f);
    float var = sq * (1.f / 512.f) - mu * mu;
    float rs = rsqrtf(var + 1e-5f);
    const float4* g4 = (const float4*)g;
    const float4* b4 = (const float4*)b;
    float4 gv = g4[lane], bv = b4[lane];
    ushort4 o;
    o.x = f2bf((v0.x - mu) * rs * gv.x + bv.x);
    o.y = f2bf((v0.y - mu) * rs * gv.y + bv.y);
    o.z = f2bf((v0.z - mu) * rs * gv.z + bv.z);
    o.w = f2bf((v0.w - mu) * rs * gv.w + bv.w);
    ((ushort4*)(out + row * 512))[lane] = o;
    gv = g4[lane + 64]; bv = b4[lane + 64];
    o.x = f2bf((v1.x - mu) * rs * gv.x + bv.x);
    o.y = f2bf((v1.y - mu) * rs * gv.y + bv.y);
    o.z = f2bf((v1.z - mu) * rs * gv.z + bv.z);
    o.w = f2bf((v1.w - mu) * rs * gv.w + bv.w);
    ((ushort4*)(out + row * 512))[lane + 64] = o;
}

// ================= R15-exact 256x256 4-phase GEMM =================
template <int EPI, int K>
__global__ __launch_bounds__(512, 1) void gemm256(const U16* __restrict__ A,
                                                  const U16* __restrict__ Bt,
                                                  const float* __restrict__ bias,
                                                  const float* __restrict__ resid,
                                                  U16* __restrict__ outb,
                                                  float* __restrict__ outf,
                                                  int M, int N, int gridN) {
    __shared__ __align__(16) U16 smem[65536];

    const int tid = threadIdx.x;
    const int lane = tid & 63, wv = tid >> 6;
    const int lo = lane & 15, hi = lane >> 4;
    const int wm = wv >> 2, wn = wv & 3;

    const int nwg = gridDim.x, bid = blockIdx.x;
    const int swzb = (bid & 7) * (nwg >> 3) + (bid >> 3);
    const int bn = swzb % gridN, bm = swzb / gridN;

    const int sr2 = tid >> 3;
    const int lc8 = (tid & 7) ^ (sr2 & 7);
    const U16* gAh = A + (size_t)(bm * 256 + sr2) * K + lc8 * 8;
    const U16* gBh = Bt + (size_t)(bn * 256 + sr2) * K + lc8 * 8;

#define SA0(t)                                                              \
    do { U16* _l = smem + ((t) & 1) * 32768 + tid * 8;                      \
         gld16(gAh + (t) * 64, _l);                                         \
         gld16(gAh + (size_t)64 * K + (t) * 64, _l + 4096); } while (0)
#define SA1(t)                                                              \
    do { U16* _l = smem + ((t) & 1) * 32768 + 8192 + tid * 8;               \
         gld16(gAh + (size_t)128 * K + (t) * 64, _l);                       \
         gld16(gAh + (size_t)192 * K + (t) * 64, _l + 4096); } while (0)
#define SB0(t)                                                              \
    do { U16* _l = smem + ((t) & 1) * 32768 + 16384 + tid * 8;              \
         gld16(gBh + (t) * 64, _l);                                         \
         gld16(gBh + (size_t)64 * K + (t) * 64, _l + 4096); } while (0)
#define SB1(t)                                                              \
    do { U16* _l = smem + ((t) & 1) * 32768 + 24576 + tid * 8;              \
         gld16(gBh + (size_t)128 * K + (t) * 64, _l);                       \
         gld16(gBh + (size_t)192 * K + (t) * 64, _l + 4096); } while (0)

    const int ck0 = (hi ^ (lo & 7)) << 3;
    const int ck1 = ((4 | hi) ^ (lo & 7)) << 3;
    const int abase = wm * 8192 + lo * 64;
    const int bbase = 16384 + (wn >> 1) * 8192 + ((wn & 1) * 64 + lo) * 64;

    f32x4 acc[8][4] = {};

    constexpr int NT = K >> 6;
    static_assert(NT >= 4 && (NT % 4) == 0, "K must be a multiple of 256");

    SA0(0); SA1(0); SB0(0); SB1(0);
    SB0(1); SB1(1);
    asm volatile("s_waitcnt vmcnt(4)" ::: "memory");
    __builtin_amdgcn_s_barrier();

#define ITER(s)                                                                 \
    do {                                                                        \
        const int _cb = ((s) & 1) * 32768;                                      \
        const U16* _Ab = smem + _cb + abase;                                    \
        const U16* _Bb = smem + _cb + bbase;                                    \
        bf16x8 af[4][2], bg[4][2], af2[4][2];                                   \
        _Pragma("unroll") for (int i = 0; i < 4; ++i) {                         \
            af[i][0] = *(const bf16x8*)(_Ab + i * 1024 + ck0);                  \
            af[i][1] = *(const bf16x8*)(_Ab + i * 1024 + ck1);                  \
        }                                                                       \
        _Pragma("unroll") for (int j = 0; j < 2; ++j) {                         \
            bg[j][0] = *(const bf16x8*)(_Bb + j * 1024 + ck0);                  \
            bg[j][1] = *(const bf16x8*)(_Bb + j * 1024 + ck1);                  \
        }                                                                       \
        if ((s) + 1 < NT) SA0((s) + 1);                                         \
        __builtin_amdgcn_s_barrier();                                           \
        __builtin_amdgcn_s_setprio(1);                                          \
        _Pragma("unroll") for (int i = 0; i < 4; ++i)                           \
            _Pragma("unroll") for (int j = 0; j < 2; ++j) {                     \
                acc[i][j] = MFMA_BF16(af[i][0], bg[j][0], acc[i][j], 0, 0, 0);  \
                acc[i][j] = MFMA_BF16(af[i][1], bg[j][1], acc[i][j], 0, 0, 0);  \
            }                                                                   \
        __builtin_amdgcn_s_setprio(0);                                          \
        __builtin_amdgcn_s_barrier();                                           \
        _Pragma("unroll") for (int j = 2; j < 4; ++j) {                         \
            bg[j][0] = *(const bf16x8*)(_Bb + j * 1024 + ck0);                  \
            bg[j][1] = *(const bf16x8*)(_Bb + j * 1024 + ck1);                  \
        }                                                                       \
        if ((s) + 1 < NT) SA1((s) + 1);                                         \
        __builtin_amdgcn_s_barrier();                                           \
        __builtin_amdgcn_s_setprio(1);                                          \
        _Pragma("unroll") for (int i = 0; i < 4; ++i)                           \
            _Pragma("unroll") for (int j = 2; j < 4; ++j) {                     \
                acc[i][j] = MFMA_BF16(af[i][0], bg[j][0], acc[i][j], 0, 0, 0);  \
                acc[i][j] = MFMA_BF16(af[i][1], bg[j][1], acc[i][j], 0, 0, 0);  \
            }                                                                   \
        __builtin_amdgcn_s_setprio(0);                                          \
        __builtin_amdgcn_s_barrier();                                           \
        _Pragma("unroll") for (int i = 0; i < 4; ++i) {                         \
            af2[i][0] = *(const bf16x8*)(_Ab + 4096 + i * 1024 + ck0);          \
            af2[i][1] = *(const bf16x8*)(_Ab + 4096 + i * 1024 + ck1);          \
        }                                                                       \
        if ((s) + 2 < NT) SB0((s) + 2);                                         \
        __builtin_amdgcn_s_barrier();                                           \
        __builtin_amdgcn_s_setprio(1);                                          \
        _Pragma("unroll") for (int i = 0; i < 4; ++i)                           \
            _Pragma("unroll") for (int j = 0; j < 2; ++j) {                     \
                acc[4 + i][j] = MFMA_BF16(af2[i][0], bg[j][0], acc[4 + i][j], 0, 0, 0); \
                acc[4 + i][j] = MFMA_BF16(af2[i][1], bg[j][1], acc[4 + i][j], 0, 0, 0); \
            }                                                                   \
        __builtin_amdgcn_s_setprio(0);                                          \
        __builtin_amdgcn_s_barrier();                                           \
        if ((s) + 2 < NT) SB1((s) + 2);                                         \
        __builtin_amdgcn_s_setprio(1);                                          \
        _Pragma("unroll") for (int i = 0; i < 4; ++i)                           \
            _Pragma("unroll") for (int j = 2; j < 4; ++j) {                     \
                acc[4 + i][j] = MFMA_BF16(af2[i][0], bg[j][0], acc[4 + i][j], 0, 0, 0); \
                acc[4 + i][j] = MFMA_BF16(af2[i][1], bg[j][1], acc[4 + i][j], 0, 0, 0); \
            }                                                                   \
        __builtin_amdgcn_s_setprio(0);                                          \
        if ((s) + 2 < NT) {                                                     \
            asm volatile("s_waitcnt vmcnt(4)" ::: "memory");                    \
        } else {                                                                \
            asm volatile("s_waitcnt vmcnt(0)" ::: "memory");                    \
        }                                                                       \
        __builtin_amdgcn_s_barrier();                                           \
    } while (0)

#pragma unroll
    for (int s = 0; s < NT; ++s) ITER(s);

    const int row0 = bm * 256 + wm * 128 + hi * 4;
    const int col0 = bn * 256 + wn * 64 + lo;
    float bc[4];
#pragma unroll
    for (int j = 0; j < 4; ++j) bc[j] = bias[col0 + j * 16];

    if (EPI == 1) {
#pragma unroll
        for (int i = 0; i < 8; ++i)
#pragma unroll
            for (int r = 0; r < 4; ++r) {
                const size_t rowb = (size_t)(row0 + i * 16 + r) * N;
#pragma unroll
                for (int j = 0; j < 4; ++j) {
                    const size_t idx = rowb + col0 + j * 16;
                    outf[idx] = acc[i][j][r] + bc[j] + resid[idx];
                }
            }
    } else {
#pragma unroll
        for (int i = 0; i < 8; ++i)
#pragma unroll
            for (int j = 0; j < 4; ++j)
#pragma unroll
                for (int r = 0; r < 4; ++r) {
                    float v = acc[i][j][r] + bc[j];
                    if (EPI == 2) {
                        float u = v * (0.7978845608028654f + 0.0356774081f * v * v);
                        v = v / (1.f + __expf(-2.f * u));
                    }
                    outb[(size_t)(row0 + i * 16 + r) * N + col0 + j * 16] = f2bf(v);
                }
    }
#undef ITER
#undef SA0
#undef SA1
#undef SB0
#undef SB1
}

// ================= fused proj + residual + LN2 (R16-validated) =================
// Block = 128 rows x FULL N=512. 512 threads = 8 waves (1x8), BK=32, ring-3 LDS.
// Writes x2 (fp32) -> d_out and h2 (bf16) in-place into hbuf.
template <int K>
__global__ __launch_bounds__(512, 1) void projln_kernel(const U16* __restrict__ A,
                                                        const U16* __restrict__ Bt,
                                                        const float* __restrict__ bias,
                                                        const float* __restrict__ x,
                                                        const float* __restrict__ g2,
                                                        const float* __restrict__ b2,
                                                        float* __restrict__ xout,
                                                        U16* __restrict__ h2out) {
    __shared__ __align__(16) U16 smem[61440];
    __shared__ float red[2304];

    const int tid = threadIdx.x;
    const int lane = tid & 63, wv = tid >> 6;
    const int lo = lane & 15, hi = lane >> 4;

    const int nwg = gridDim.x, bid = blockIdx.x;
    const int bm = (bid & 7) * (nwg >> 3) + (bid >> 3);

    const int sr = tid >> 2;
    const int lc = (tid & 3) ^ ((sr >> 1) & 3);
    const U16* gA0 = A + (size_t)(bm * 128 + sr) * K + lc * 8;
    const U16* gB0 = Bt + (size_t)sr * K + lc * 8;
    const U16* gB1 = gB0 + (size_t)128 * K;
    const U16* gB2 = gB0 + (size_t)256 * K;
    const U16* gB3 = gB0 + (size_t)384 * K;

#define PSTAGE(t2)                                                    \
    do {                                                              \
        U16* _l = smem + ((t2) % 3) * 20480 + tid * 8;                \
        gld16(gA0 + (t2) * 32, _l);                                   \
        gld16(gB0 + (t2) * 32, _l + 4096);                            \
        gld16(gB1 + (t2) * 32, _l + 8192);                            \
        gld16(gB2 + (t2) * 32, _l + 12288);                           \
        gld16(gB3 + (t2) * 32, _l + 16384);                           \
    } while (0)

    const int ck = (hi ^ ((lo >> 1) & 3)) << 3;
    const int aoff = lo * 32 + ck;
    const int boff = 4096 + (wv * 64 + lo) * 32 + ck;

    f32x4 acc[8][4] = {};

    constexpr int NT = K >> 5;
    static_assert(NT == 16, "projln expects K=512");

    PSTAGE(0);
    PSTAGE(1);

#define PITER(t)                                                                \
    do {                                                                        \
        if ((t) + 1 < NT) {                                                     \
            asm volatile("s_waitcnt vmcnt(5)" ::: "memory");                    \
        } else {                                                                \
            asm volatile("s_waitcnt vmcnt(0)" ::: "memory");                    \
        }                                                                       \
        __builtin_amdgcn_s_barrier();                                           \
        if ((t) + 2 < NT) PSTAGE((t) + 2);                                      \
        {                                                                       \
            const int _cb = ((t) % 3) * 20480;                                  \
            const U16* _Ab = smem + _cb + aoff;                                 \
            const U16* _Bb = smem + _cb + boff;                                 \
            bf16x8 af[8], bg[4];                                                \
            _Pragma("unroll") for (int i = 0; i < 8; ++i)                       \
                af[i] = *(const bf16x8*)(_Ab + i * 512);                        \
            _Pragma("unroll") for (int j = 0; j < 4; ++j)                       \
                bg[j] = *(const bf16x8*)(_Bb + j * 512);                        \
            __builtin_amdgcn_s_setprio(1);                                      \
            _Pragma("unroll") for (int i = 0; i < 8; ++i)                       \
                _Pragma("unroll") for (int j = 0; j < 4; ++j)                   \
                    acc[i][j] = MFMA_BF16(af[i], bg[j], acc[i][j], 0, 0, 0);    \
            __builtin_amdgcn_s_setprio(0);                                      \
        }                                                                       \
    } while (0)

#pragma unroll
    for (int t = 0; t < NT; ++t) PITER(t);

    const size_t row0g = (size_t)bm * 128;
    float bc[4];
#pragma unroll
    for (int j = 0; j < 4; ++j) bc[j] = bias[wv * 64 + j * 16 + lo];

#pragma unroll
    for (int i = 0; i < 8; ++i)
#pragma unroll
        for (int r = 0; r < 4; ++r) {
            const int row = i * 16 + hi * 4 + r;
            const size_t rowb = (row0g + row) * 512;
            float s = 0.f, sq = 0.f;
#pragma unroll
            for (int j = 0; j < 4; ++j) {
                const int col = wv * 64 + j * 16 + lo;
                float v = acc[i][j][r] + bc[j] + x[rowb + col];
                acc[i][j][r] = v;
                xout[rowb + col] = v;
                s += v; sq += v * v;
            }
#pragma unroll
            for (int m = 1; m < 16; m <<= 1) { s += __shfl_xor(s, m); sq += __shfl_xor(sq, m); }
            if (lo == 0) { red[row * 8 + wv] = s; red[1024 + row * 8 + wv] = sq; }
        }
    __syncthreads();
    if (tid < 128) {
        float s = 0.f, q = 0.f;
#pragma unroll
        for (int w = 0; w < 8; ++w) { s += red[tid * 8 + w]; q += red[1024 + tid * 8 + w]; }
        float mu = s * (1.f / 512.f);
        float var = q * (1.f / 512.f) - mu * mu;
        red[2048 + tid] = mu;
        red[2176 + tid] = rsqrtf(var + 1e-5f);
    }
    __syncthreads();
    float gv[4], bv[4];
#pragma unroll
    for (int j = 0; j < 4; ++j) {
        const int col = wv * 64 + j * 16 + lo;
        gv[j] = g2[col]; bv[j] = b2[col];
    }
#pragma unroll
    for (int i = 0; i < 8; ++i)
#pragma unroll
        for (int r = 0; r < 4; ++r) {
            const int row = i * 16 + hi * 4 + r;
            const float mu = red[2048 + row];
            const float rs = red[2176 + row];
            const size_t rowb = (row0g + row) * 512;
#pragma unroll
            for (int j = 0; j < 4; ++j) {
                const int col = wv * 64 + j * 16 + lo;
                h2out[rowb + col] = f2bf((acc[i][j][r] - mu) * rs * gv[j] + bv[j]);
            }
        }
#undef PITER
#undef PSTAGE
}

// ---------------- windowed attention: one block per (window, head) ----------------
__global__ __launch_bounds__(256) void attn_kernel(const U16* __restrict__ qkv,
                                                   U16* __restrict__ o) {
    const int blk = blockIdx.x;
    const int w = blk >> 3, h = blk & 7;
    const int tid = threadIdx.x;
    const int lane = tid & 63, wv = tid >> 6;
    const int lo = lane & 15, hi = lane >> 4;

    __shared__ __align__(16) U16 Qs[64][72];
    __shared__ __align__(16) U16 Ks[64][72];
    __shared__ __align__(16) U16 Vt[64][72];
    __shared__ __align__(16) U16 Ps[4][16][72];

    {
        const int r = tid >> 2;
        const int c0 = (tid & 3) << 4;
        const U16* p = qkv + (size_t)(w * 64 + r) * 1536 + h * 64 + c0;
        *(bf16x8*)&Ks[r][c0] = *(const bf16x8*)(p + 512);
        *(bf16x8*)&Ks[r][c0 + 8] = *(const bf16x8*)(p + 520);
        const U16* pv = p + 1024;
#pragma unroll
        for (int i = 0; i < 16; i++) Vt[c0 + i][r] = pv[i];
#pragma unroll
        for (int i = 0; i < 16; i++) Qs[r][c0 + i] = f2bf(bf2f(p[i]) * 0.125f);
    }
    __syncthreads();

    const int rb = wv * 16;
    f32x4 s[4] = {};
#pragma unroll
    for (int dc = 0; dc < 64; dc += 32) {
        bf16x8 a = *(const bf16x8*)&Qs[rb + lo][dc + hi * 8];
#pragma unroll
        for (int jb = 0; jb < 4; jb++) {
            bf16x8 bfr = *(const bf16x8*)&Ks[jb * 16 + lo][dc + hi * 8];
            s[jb] = MFMA_BF16(a, bfr, s[jb], 0, 0, 0);
        }
    }
#pragma unroll
    for (int r = 0; r < 4; r++) {
        float m = fmaxf(fmaxf(s[0][r], s[1][r]), fmaxf(s[2][r], s[3][r]));
#pragma unroll
        for (int msk = 1; msk < 16; msk <<= 1) m = fmaxf(m, __shfl_xor(m, msk));
        float e[4], sum = 0.f;
#pragma unroll
        for (int jb = 0; jb < 4; jb++) { e[jb] = __expf(s[jb][r] - m); sum += e[jb]; }
#pragma unroll
        for (int msk = 1; msk < 16; msk <<= 1) sum += __shfl_xor(sum, msk);
        float inv = 1.f / sum;
#pragma unroll
        for (int jb = 0; jb < 4; jb++) Ps[wv][hi * 4 + r][jb * 16 + lo] = f2bf(e[jb] * inv);
    }
    __syncthreads();

    f32x4 oa[4] = {};
#pragma unroll
    for (int jc = 0; jc < 64; jc += 32) {
        bf16x8 a = *(const bf16x8*)&Ps[wv][lo][jc + hi * 8];
#pragma unroll
        for (int db = 0; db < 4; db++) {
            bf16x8 bfr = *(const bf16x8*)&Vt[db * 16 + lo][jc + hi * 8];
            oa[db] = MFMA_BF16(a, bfr, oa[db], 0, 0, 0);
        }
    }
#pragma unroll
    for (int db = 0; db < 4; db++)
#pragma unroll
        for (int r = 0; r < 4; r++)
            o[(size_t)(w * 64 + rb + hi * 4 + r) * 512 + h * 64 + db * 16 + lo] = f2bf(oa[db][r]);
}

// ---------------- launch ----------------
extern "C" void kernel_launch(void* const* d_in, const int* in_sizes, int n_in,
                              void* d_out, int out_size, void* d_ws, size_t ws_size,
                              hipStream_t stream) {
    const float* x = (const float*)d_in[0];
    const float* ln1_g = (const float*)d_in[1];
    const float* ln1_b = (const float*)d_in[2];
    const float* qkv_w = (const float*)d_in[3];
    const float* qkv_b = (const float*)d_in[4];
    const float* proj_w = (const float*)d_in[5];
    const float* proj_b = (const float*)d_in[6];
    const float* ln2_g = (const float*)d_in[7];
    const float* ln2_b = (const float*)d_in[8];
    const float* fc1_w = (const float*)d_in[9];
    const float* fc1_b = (const float*)d_in[10];
    const float* fc2_w = (const float*)d_in[11];
    const float* fc2_b = (const float*)d_in[12];
    float* out = (float*)d_out;

    char* ws = (char*)d_ws;
    U16* hbuf = (U16*)ws;                               // 32768*512 bf16 (h -> o -> h2)
    U16* big = (U16*)(ws + 33554432);                   // qkv then fc1 act
    U16* wt_qkv = (U16*)(ws + 33554432 + 134217728);
    U16* wt_proj = wt_qkv + 1536 * 512;
    U16* wt_fc1 = wt_proj + 512 * 512;
    U16* wt_fc2 = wt_fc1 + 2048 * 512;

    dim3 tb(32, 8);
    tcast_kernel<<<dim3(1536 / 32, 512 / 32), tb, 0, stream>>>(qkv_w, wt_qkv, 512, 1536);
    tcast_kernel<<<dim3(512 / 32, 512 / 32), tb, 0, stream>>>(proj_w, wt_proj, 512, 512);
    tcast_kernel<<<dim3(2048 / 32, 512 / 32), tb, 0, stream>>>(fc1_w, wt_fc1, 512, 2048);
    tcast_kernel<<<dim3(512 / 32, 2048 / 32), tb, 0, stream>>>(fc2_w, wt_fc2, 2048, 512);

    ln_kernel<<<8192, 256, 0, stream>>>(x, ln1_g, ln1_b, hbuf);
    gemm256<0, 512><<<768, 512, 0, stream>>>(hbuf, wt_qkv, qkv_b, nullptr, big, nullptr, 32768, 1536, 6);
    attn_kernel<<<4096, 256, 0, stream>>>(big, hbuf);
    // fused proj + residual + LN2: writes x2 (fp32) -> d_out, h2 (bf16) in-place -> hbuf
    projln_kernel<512><<<256, 512, 0, stream>>>(hbuf, wt_proj, proj_b, x, ln2_g, ln2_b, out, hbuf);
    gemm256<2, 512><<<1024, 512, 0, stream>>>(hbuf, wt_fc1, fc1_b, nullptr, big, nullptr, 32768, 2048, 8);
    gemm256<1, 2048><<<256, 512, 0, stream>>>(big, wt_fc2, fc2_b, out, nullptr, out, 32768, 512, 2);
}

// Round 18
// 350.759 us; speedup vs baseline: 1.0812x; 1.0394x over previous
//
#include <hip/hip_runtime.h>
#include <hip/hip_bf16.h>
#include <cstdint>

typedef unsigned short U16;
typedef float f32x4 __attribute__((ext_vector_type(4)));
typedef __bf16 bf16x8 __attribute__((ext_vector_type(8)));

#define DEVINL __device__ __forceinline__

DEVINL U16 f2bf(float f) {
    unsigned u = __float_as_uint(f);
    return (U16)((u + 0x7FFFu + ((u >> 16) & 1u)) >> 16);  // RN-even
}
DEVINL float bf2f(U16 s) { return __uint_as_float(((unsigned)s) << 16); }

DEVINL void gld16(const void* g, void* l) {
    __builtin_amdgcn_global_load_lds(
        (const __attribute__((address_space(1))) void*)g,
        (__attribute__((address_space(3))) void*)l, 16, 0, 0);
}

#define MFMA_BF16 __builtin_amdgcn_mfma_f32_16x16x32_bf16

// ---------------- weight transpose + cast: wt[n][k] = (bf16) w[k][n] ----------------
__global__ __launch_bounds__(256) void tcast_kernel(const float* __restrict__ w,
                                                    U16* __restrict__ wt, int K, int N) {
    __shared__ float tile[32][33];
    int n0 = blockIdx.x * 32, k0 = blockIdx.y * 32;
    int tx = threadIdx.x, ty = threadIdx.y;  // 32 x 8
#pragma unroll
    for (int i = 0; i < 32; i += 8) tile[ty + i][tx] = w[(size_t)(k0 + ty + i) * N + (n0 + tx)];
    __syncthreads();
#pragma unroll
    for (int i = 0; i < 32; i += 8) wt[(size_t)(n0 + ty + i) * K + (k0 + tx)] = f2bf(tile[tx][ty + i]);
}

// ---------------- LayerNorm over 512, one wave per row, bf16 out ----------------
__global__ __launch_bounds__(256) void ln_kernel(const float* __restrict__ x,
                                                 const float* __restrict__ g,
                                                 const float* __restrict__ b,
                                                 U16* __restrict__ out) {
    int lane = threadIdx.x & 63;
    size_t row = (size_t)blockIdx.x * 4 + (threadIdx.x >> 6);
    const float4* xr = (const float4*)(x + row * 512);
    float4 v0 = xr[lane], v1 = xr[lane + 64];
    float s = (v0.x + v0.y) + (v0.z + v0.w) + (v1.x + v1.y) + (v1.z + v1.w);
    float sq = (v0.x * v0.x + v0.y * v0.y + v0.z * v0.z + v0.w * v0.w) +
               (v1.x * v1.x + v1.y * v1.y + v1.z * v1.z + v1.w * v1.w);
#pragma unroll
    for (int m = 1; m < 64; m <<= 1) { s += __shfl_xor(s, m); sq += __shfl_xor(sq, m); }
    float mu = s * (1.f / 512.f);
    float var = sq * (1.f / 512.f) - mu * mu;
    float rs = rsqrtf(var + 1e-5f);
    const float4* g4 = (const float4*)g;
    const float4* b4 = (const float4*)b;
    float4 gv = g4[lane], bv = b4[lane];
    ushort4 o;
    o.x = f2bf((v0.x - mu) * rs * gv.x + bv.x);
    o.y = f2bf((v0.y - mu) * rs * gv.y + bv.y);
    o.z = f2bf((v0.z - mu) * rs * gv.z + bv.z);
    o.w = f2bf((v0.w - mu) * rs * gv.w + bv.w);
    ((ushort4*)(out + row * 512))[lane] = o;
    gv = g4[lane + 64]; bv = b4[lane + 64];
    o.x = f2bf((v1.x - mu) * rs * gv.x + bv.x);
    o.y = f2bf((v1.y - mu) * rs * gv.y + bv.y);
    o.z = f2bf((v1.z - mu) * rs * gv.z + bv.z);
    o.w = f2bf((v1.w - mu) * rs * gv.w + bv.w);
    ((ushort4*)(out + row * 512))[lane + 64] = o;
}

// ---------------- 256x256 m201-faithful 4-phase/BK=64 GEMM (R15, best measured) --------
// C[M,N] = A[M,K](bf16) * Bt[N,K](bf16)^T + bias (+gelu / +resid)
// 512 threads = 8 waves (2M x 4N), wave tile 128x64, BK=64, 2 x 64KB dbuf (128KB).
// Per tile s, 4 quadrant phases; stage targets by slot-death analysis; counted vmcnt(4)
// once per tile (never drains mid-loop). Swizzle = R4-verified 8-chunk XOR (0 conflicts).
// EPI 0: bf16 out (bias); EPI 1: fp32 out (bias+resid); EPI 2: bf16 out (bias+gelu-tanh)
template <int EPI, int K>
__global__ __launch_bounds__(512, 1) void gemm_rt(const U16* __restrict__ A,
                                                  const U16* __restrict__ Bt,
                                                  const float* __restrict__ bias,
                                                  const float* __restrict__ resid,
                                                  U16* __restrict__ outb,
                                                  float* __restrict__ outf,
                                                  int M, int N, int gridN) {
    __shared__ __align__(16) U16 smem[65536];

    const int tid = threadIdx.x;
    const int lane = tid & 63, wv = tid >> 6;
    const int lo = lane & 15, hi = lane >> 4;
    const int wm = wv >> 2, wn = wv & 3;  // 2 x 4 wave grid, wave tile 128x64

    const int nwg = gridDim.x, bid = blockIdx.x;
    const int swzb = (bid & 7) * (nwg >> 3) + (bid >> 3);
    const int bn = swzb % gridN, bm = swzb / gridN;

    const int sr2 = tid >> 3;
    const int lc8 = (tid & 7) ^ (sr2 & 7);
    const U16* gAh = A + (size_t)(bm * 256 + sr2) * K + lc8 * 8;
    const U16* gBh = Bt + (size_t)(bn * 256 + sr2) * K + lc8 * 8;

#define SA0(t)                                                              \
    do { U16* _l = smem + ((t) & 1) * 32768 + tid * 8;                      \
         gld16(gAh + (t) * 64, _l);                                         \
         gld16(gAh + (size_t)64 * K + (t) * 64, _l + 4096); } while (0)
#define SA1(t)                                                              \
    do { U16* _l = smem + ((t) & 1) * 32768 + 8192 + tid * 8;               \
         gld16(gAh + (size_t)128 * K + (t) * 64, _l);                       \
         gld16(gAh + (size_t)192 * K + (t) * 64, _l + 4096); } while (0)
#define SB0(t)                                                              \
    do { U16* _l = smem + ((t) & 1) * 32768 + 16384 + tid * 8;              \
         gld16(gBh + (t) * 64, _l);                                         \
         gld16(gBh + (size_t)64 * K + (t) * 64, _l + 4096); } while (0)
#define SB1(t)                                                              \
    do { U16* _l = smem + ((t) & 1) * 32768 + 24576 + tid * 8;              \
         gld16(gBh + (size_t)128 * K + (t) * 64, _l);                       \
         gld16(gBh + (size_t)192 * K + (t) * 64, _l + 4096); } while (0)

    const int ck0 = (hi ^ (lo & 7)) << 3;
    const int ck1 = ((4 | hi) ^ (lo & 7)) << 3;
    const int abase = wm * 8192 + lo * 64;
    const int bbase = 16384 + (wn >> 1) * 8192 + ((wn & 1) * 64 + lo) * 64;

    f32x4 acc[8][4] = {};

    constexpr int NT = K >> 6;
    static_assert(NT >= 4 && (NT % 4) == 0, "K must be a multiple of 256");

    SA0(0); SA1(0); SB0(0); SB1(0);
    SB0(1); SB1(1);
    asm volatile("s_waitcnt vmcnt(4)" ::: "memory");
    __builtin_amdgcn_s_barrier();

#define ITER(s)                                                                 \
    do {                                                                        \
        const int _cb = ((s) & 1) * 32768;                                      \
        const U16* _Ab = smem + _cb + abase;                                    \
        const U16* _Bb = smem + _cb + bbase;                                    \
        bf16x8 af[4][2], bg[4][2], af2[4][2];                                   \
        _Pragma("unroll") for (int i = 0; i < 4; ++i) {                         \
            af[i][0] = *(const bf16x8*)(_Ab + i * 1024 + ck0);                  \
            af[i][1] = *(const bf16x8*)(_Ab + i * 1024 + ck1);                  \
        }                                                                       \
        _Pragma("unroll") for (int j = 0; j < 2; ++j) {                         \
            bg[j][0] = *(const bf16x8*)(_Bb + j * 1024 + ck0);                  \
            bg[j][1] = *(const bf16x8*)(_Bb + j * 1024 + ck1);                  \
        }                                                                       \
        if ((s) + 1 < NT) SA0((s) + 1);                                         \
        __builtin_amdgcn_s_barrier();                                           \
        __builtin_amdgcn_s_setprio(1);                                          \
        _Pragma("unroll") for (int i = 0; i < 4; ++i)                           \
            _Pragma("unroll") for (int j = 0; j < 2; ++j) {                     \
                acc[i][j] = MFMA_BF16(af[i][0], bg[j][0], acc[i][j], 0, 0, 0);  \
                acc[i][j] = MFMA_BF16(af[i][1], bg[j][1], acc[i][j], 0, 0, 0);  \
            }                                                                   \
        __builtin_amdgcn_s_setprio(0);                                          \
        __builtin_amdgcn_s_barrier();                                           \
        _Pragma("unroll") for (int j = 2; j < 4; ++j) {                         \
            bg[j][0] = *(const bf16x8*)(_Bb + j * 1024 + ck0);                  \
            bg[j][1] = *(const bf16x8*)(_Bb + j * 1024 + ck1);                  \
        }                                                                       \
        if ((s) + 1 < NT) SA1((s) + 1);                                         \
        __builtin_amdgcn_s_barrier();                                           \
        __builtin_amdgcn_s_setprio(1);                                          \
        _Pragma("unroll") for (int i = 0; i < 4; ++i)                           \
            _Pragma("unroll") for (int j = 2; j < 4; ++j) {                     \
                acc[i][j] = MFMA_BF16(af[i][0], bg[j][0], acc[i][j], 0, 0, 0);  \
                acc[i][j] = MFMA_BF16(af[i][1], bg[j][1], acc[i][j], 0, 0, 0);  \
            }                                                                   \
        __builtin_amdgcn_s_setprio(0);                                          \
        __builtin_amdgcn_s_barrier();                                           \
        _Pragma("unroll") for (int i = 0; i < 4; ++i) {                         \
            af2[i][0] = *(const bf16x8*)(_Ab + 4096 + i * 1024 + ck0);          \
            af2[i][1] = *(const bf16x8*)(_Ab + 4096 + i * 1024 + ck1);          \
        }                                                                       \
        if ((s) + 2 < NT) SB0((s) + 2);                                         \
        __builtin_amdgcn_s_barrier();                                           \
        __builtin_amdgcn_s_setprio(1);                                          \
        _Pragma("unroll") for (int i = 0; i < 4; ++i)                           \
            _Pragma("unroll") for (int j = 0; j < 2; ++j) {                     \
                acc[4 + i][j] = MFMA_BF16(af2[i][0], bg[j][0], acc[4 + i][j], 0, 0, 0); \
                acc[4 + i][j] = MFMA_BF16(af2[i][1], bg[j][1], acc[4 + i][j], 0, 0, 0); \
            }                                                                   \
        __builtin_amdgcn_s_setprio(0);                                          \
        __builtin_amdgcn_s_barrier();                                           \
        if ((s) + 2 < NT) SB1((s) + 2);                                         \
        __builtin_amdgcn_s_setprio(1);                                          \
        _Pragma("unroll") for (int i = 0; i < 4; ++i)                           \
            _Pragma("unroll") for (int j = 2; j < 4; ++j) {                     \
                acc[4 + i][j] = MFMA_BF16(af2[i][0], bg[j][0], acc[4 + i][j], 0, 0, 0); \
                acc[4 + i][j] = MFMA_BF16(af2[i][1], bg[j][1], acc[4 + i][j], 0, 0, 0); \
            }                                                                   \
        __builtin_amdgcn_s_setprio(0);                                          \
        if ((s) + 2 < NT) {                                                     \
            asm volatile("s_waitcnt vmcnt(4)" ::: "memory");                    \
        } else {                                                                \
            asm volatile("s_waitcnt vmcnt(0)" ::: "memory");                    \
        }                                                                       \
        __builtin_amdgcn_s_barrier();                                           \
    } while (0)

#pragma unroll
    for (int s = 0; s < NT; ++s) ITER(s);

    const int row0 = bm * 256 + wm * 128 + hi * 4;
    const int col0 = bn * 256 + wn * 64 + lo;
    float bc[4];
#pragma unroll
    for (int j = 0; j < 4; ++j) bc[j] = bias[col0 + j * 16];

    if (EPI == 1) {
#pragma unroll
        for (int i = 0; i < 8; ++i)
#pragma unroll
            for (int r = 0; r < 4; ++r) {
                const size_t rowb = (size_t)(row0 + i * 16 + r) * N;
#pragma unroll
                for (int j = 0; j < 4; ++j) {
                    const size_t idx = rowb + col0 + j * 16;
                    outf[idx] = acc[i][j][r] + bc[j] + resid[idx];
                }
            }
    } else {
#pragma unroll
        for (int i = 0; i < 8; ++i)
#pragma unroll
            for (int j = 0; j < 4; ++j)
#pragma unroll
                for (int r = 0; r < 4; ++r) {
                    float v = acc[i][j][r] + bc[j];
                    if (EPI == 2) {
                        // tanh-form GELU: v*sigmoid(2u), u = 0.79788456(v + 0.044715 v^3)
                        float u = v * (0.7978845608028654f + 0.0356774081f * v * v);
                        v = v / (1.f + __expf(-2.f * u));
                    }
                    outb[(size_t)(row0 + i * 16 + r) * N + col0 + j * 16] = f2bf(v);
                }
    }
#undef ITER
#undef SA0
#undef SA1
#undef SB0
#undef SB1
}

// ---------------- windowed attention: one block per (window, head) ----------------
// qkv: [32768][1536] bf16, layout [3][8][64] in last dim. o: [32768][512] bf16.
__global__ __launch_bounds__(256) void attn_kernel(const U16* __restrict__ qkv,
                                                   U16* __restrict__ o) {
    const int blk = blockIdx.x;
    const int w = blk >> 3, h = blk & 7;
    const int tid = threadIdx.x;
    const int lane = tid & 63, wv = tid >> 6;
    const int lo = lane & 15, hi = lane >> 4;

    __shared__ __align__(16) U16 Qs[64][72];
    __shared__ __align__(16) U16 Ks[64][72];
    __shared__ __align__(16) U16 Vt[64][72];  // V transposed: Vt[d][j]
    __shared__ __align__(16) U16 Ps[4][16][72];

    {
        const int r = tid >> 2;
        const int c0 = (tid & 3) << 4;
        const U16* p = qkv + (size_t)(w * 64 + r) * 1536 + h * 64 + c0;
        *(bf16x8*)&Ks[r][c0] = *(const bf16x8*)(p + 512);
        *(bf16x8*)&Ks[r][c0 + 8] = *(const bf16x8*)(p + 520);
        const U16* pv = p + 1024;
#pragma unroll
        for (int i = 0; i < 16; i++) Vt[c0 + i][r] = pv[i];
#pragma unroll
        for (int i = 0; i < 16; i++) Qs[r][c0 + i] = f2bf(bf2f(p[i]) * 0.125f);
    }
    __syncthreads();

    const int rb = wv * 16;  // this wave's 16 score rows
    f32x4 s[4] = {};
#pragma unroll
    for (int dc = 0; dc < 64; dc += 32) {
        bf16x8 a = *(const bf16x8*)&Qs[rb + lo][dc + hi * 8];
#pragma unroll
        for (int jb = 0; jb < 4; jb++) {
            bf16x8 bfr = *(const bf16x8*)&Ks[jb * 16 + lo][dc + hi * 8];
            s[jb] = MFMA_BF16(a, bfr, s[jb], 0, 0, 0);
        }
    }
#pragma unroll
    for (int r = 0; r < 4; r++) {
        float m = fmaxf(fmaxf(s[0][r], s[1][r]), fmaxf(s[2][r], s[3][r]));
#pragma unroll
        for (int msk = 1; msk < 16; msk <<= 1) m = fmaxf(m, __shfl_xor(m, msk));
        float e[4], sum = 0.f;
#pragma unroll
        for (int jb = 0; jb < 4; jb++) { e[jb] = __expf(s[jb][r] - m); sum += e[jb]; }
#pragma unroll
        for (int msk = 1; msk < 16; msk <<= 1) sum += __shfl_xor(sum, msk);
        float inv = 1.f / sum;
#pragma unroll
        for (int jb = 0; jb < 4; jb++) Ps[wv][hi * 4 + r][jb * 16 + lo] = f2bf(e[jb] * inv);
    }
    __syncthreads();

    f32x4 oa[4] = {};
#pragma unroll
    for (int jc = 0; jc < 64; jc += 32) {
        bf16x8 a = *(const bf16x8*)&Ps[wv][lo][jc + hi * 8];
#pragma unroll
        for (int db = 0; db < 4; db++) {
            bf16x8 bfr = *(const bf16x8*)&Vt[db * 16 + lo][jc + hi * 8];
            oa[db] = MFMA_BF16(a, bfr, oa[db], 0, 0, 0);
        }
    }
#pragma unroll
    for (int db = 0; db < 4; db++)
#pragma unroll
        for (int r = 0; r < 4; r++)
            o[(size_t)(w * 64 + rb + hi * 4 + r) * 512 + h * 64 + db * 16 + lo] = f2bf(oa[db][r]);
}

// ---------------- launch ----------------
extern "C" void kernel_launch(void* const* d_in, const int* in_sizes, int n_in,
                              void* d_out, int out_size, void* d_ws, size_t ws_size,
                              hipStream_t stream) {
    const float* x = (const float*)d_in[0];
    const float* ln1_g = (const float*)d_in[1];
    const float* ln1_b = (const float*)d_in[2];
    const float* qkv_w = (const float*)d_in[3];
    const float* qkv_b = (const float*)d_in[4];
    const float* proj_w = (const float*)d_in[5];
    const float* proj_b = (const float*)d_in[6];
    const float* ln2_g = (const float*)d_in[7];
    const float* ln2_b = (const float*)d_in[8];
    const float* fc1_w = (const float*)d_in[9];
    const float* fc1_b = (const float*)d_in[10];
    const float* fc2_w = (const float*)d_in[11];
    const float* fc2_b = (const float*)d_in[12];
    float* out = (float*)d_out;

    char* ws = (char*)d_ws;
    U16* hbuf = (U16*)ws;                               // 32768*512 bf16
    U16* big = (U16*)(ws + 33554432);                   // 32768*2048 bf16 max
    U16* wt_qkv = (U16*)(ws + 33554432 + 134217728);    // 1536*512
    U16* wt_proj = wt_qkv + 1536 * 512;                 // 512*512
    U16* wt_fc1 = wt_proj + 512 * 512;                  // 2048*512
    U16* wt_fc2 = wt_fc1 + 2048 * 512;                  // 512*2048

    dim3 tb(32, 8);
    tcast_kernel<<<dim3(1536 / 32, 512 / 32), tb, 0, stream>>>(qkv_w, wt_qkv, 512, 1536);
    tcast_kernel<<<dim3(512 / 32, 512 / 32), tb, 0, stream>>>(proj_w, wt_proj, 512, 512);
    tcast_kernel<<<dim3(2048 / 32, 512 / 32), tb, 0, stream>>>(fc1_w, wt_fc1, 512, 2048);
    tcast_kernel<<<dim3(512 / 32, 2048 / 32), tb, 0, stream>>>(fc2_w, wt_fc2, 2048, 512);

    ln_kernel<<<8192, 256, 0, stream>>>(x, ln1_g, ln1_b, hbuf);
    gemm_rt<0, 512><<<768, 512, 0, stream>>>(hbuf, wt_qkv, qkv_b, nullptr, big, nullptr, 32768, 1536, 6);
    attn_kernel<<<4096, 256, 0, stream>>>(big, hbuf);
    gemm_rt<1, 512><<<256, 512, 0, stream>>>(hbuf, wt_proj, proj_b, x, nullptr, out, 32768, 512, 2);
    ln_kernel<<<8192, 256, 0, stream>>>(out, ln2_g, ln2_b, hbuf);
    gemm_rt<2, 512><<<1024, 512, 0, stream>>>(hbuf, wt_fc1, fc1_b, nullptr, big, nullptr, 32768, 2048, 8);
    gemm_rt<1, 2048><<<256, 512, 0, stream>>>(big, wt_fc2, fc2_b, out, nullptr, out, 32768, 512, 2);
}